// Round 4
// baseline (218.833 us; speedup 1.0000x reference)
//
#include <hip/hip_runtime.h>
#include <hip/hip_bf16.h>

typedef __bf16 bf16;
typedef __attribute__((ext_vector_type(8))) __bf16 bf16x8;
typedef __attribute__((ext_vector_type(4))) __bf16 bf16x4;
typedef __attribute__((ext_vector_type(16))) float f32x16;

#define N_ROWS 16384
#define DIM 256
#define NT 128               /* 128x128 tiles, upper-triangular */
#define INV_T 14.2857142857f /* 1/0.07 */
#define K1C 20.6099203f      /* 1/(0.07*ln2) */

#define WS_T_OFF (N_ROWS * DIM * 2)
#define WS_D_OFF (WS_T_OFF + N_ROWS * 4)

#define GLOAD_LDS(g, l)                                        \
    __builtin_amdgcn_global_load_lds(                          \
        (const __attribute__((address_space(1))) void*)(g),    \
        (__attribute__((address_space(3))) void*)(l), 16, 0, 0)

// Kernel 1: L2-normalize rows (fp32) -> bf16 matrix; zero T[] and d_out;
// D[row] = (1 - s2)/T with s2 = sum(bf16(a)^2) so the MFMA diagonal's bf16
// rounding error cancels in log-space.
__global__ void __launch_bounds__(256) normalize_kernel(const float* __restrict__ in,
                                                        bf16* __restrict__ out,
                                                        float* __restrict__ Tg,
                                                        float* __restrict__ Dg,
                                                        float* __restrict__ loss_out) {
    if (blockIdx.x == 0 && threadIdx.x == 0) loss_out[0] = 0.0f;
    if (blockIdx.x < 64) Tg[blockIdx.x * 256 + threadIdx.x] = 0.0f;

    const int row  = blockIdx.x * 4 + (threadIdx.x >> 6);
    const int lane = threadIdx.x & 63;
    const float4* rp = (const float4*)(in + (size_t)row * DIM);
    float4 v = rp[lane];
    float ss = v.x * v.x + v.y * v.y + v.z * v.z + v.w * v.w;
#pragma unroll
    for (int m = 1; m < 64; m <<= 1) ss += __shfl_xor(ss, m, 64);
    float inv = 1.0f / fmaxf(sqrtf(ss), 1e-12f);
    bf16x4 o;
    o[0] = (bf16)(v.x * inv);
    o[1] = (bf16)(v.y * inv);
    o[2] = (bf16)(v.z * inv);
    o[3] = (bf16)(v.w * inv);
    *(bf16x4*)(out + (size_t)row * DIM + lane * 4) = o;

    float f0 = (float)o[0], f1 = (float)o[1], f2 = (float)o[2], f3 = (float)o[3];
    float s2 = f0 * f0 + f1 * f1 + f2 * f2 + f3 * f3;
#pragma unroll
    for (int m = 1; m < 64; m <<= 1) s2 += __shfl_xor(s2, m, 64);
    if (lane == 0) Dg[row] = (1.0f - s2) * INV_T;
}

// Tree-reduce a 16-float register vector across the 32 `lo` lanes.
// After: every lane holds the full sum for register index r = (lo>>1)&15.
#define TREE16(R, out)                                                   \
    do {                                                                 \
        float w8[8], w4[4], w2[2], w1, g_;                               \
        _Pragma("unroll") for (int i_ = 0; i_ < 8; ++i_) {               \
            g_ = (lo & 16) ? R[i_] : R[i_ + 8];                          \
            w8[i_] = ((lo & 16) ? R[i_ + 8] : R[i_]) + __shfl_xor(g_, 16); \
        }                                                                \
        _Pragma("unroll") for (int i_ = 0; i_ < 4; ++i_) {               \
            g_ = (lo & 8) ? w8[i_] : w8[i_ + 4];                         \
            w4[i_] = ((lo & 8) ? w8[i_ + 4] : w8[i_]) + __shfl_xor(g_, 8); \
        }                                                                \
        _Pragma("unroll") for (int i_ = 0; i_ < 2; ++i_) {               \
            g_ = (lo & 4) ? w4[i_] : w4[i_ + 2];                         \
            w2[i_] = ((lo & 4) ? w4[i_ + 2] : w4[i_]) + __shfl_xor(g_, 4); \
        }                                                                \
        g_ = (lo & 2) ? w2[0] : w2[1];                                   \
        w1 = ((lo & 2) ? w2[1] : w2[0]) + __shfl_xor(g_, 2);             \
        out = w1 + __shfl_xor(w1, 1);                                    \
    } while (0)

// Kernel 2: symmetric fused A*A^T + fixed-shift softmax denominator.
// Upper-tri 128x128 tiles. 4 waves; wave w: rows (w>>1)*64, cols (w&1)*64
// (2x2 of 32x32x16). K staged in 4 slabs of 64, plain m97-style LDS layout
// (row-major, 64-elem rows; uniform per-(k16,hi) read offsets -> no swizzle).
// Row/col sums use tree reduction + single-writer LDS arrays (no atomics).
__global__ void __launch_bounds__(256)
loss_kernel(const bf16* __restrict__ A, float* __restrict__ Tg) {
    __shared__ bf16 As[128 * 64];
    __shared__ bf16 Bs[128 * 64];
    __shared__ float RsA[128], RsB[128], CsA[128], CsB[128];

    const int tid = threadIdx.x;
    const int w  = tid >> 6;
    const int l  = tid & 63;
    const int lo = l & 31, hi = l >> 5;

    // decode (it, jt), jt >= it, from linear upper-tri index
    const int b = blockIdx.x;
    int it = (int)(((float)(2 * NT + 1) -
                    sqrtf((float)((2 * NT + 1) * (2 * NT + 1)) - 8.0f * (float)b)) * 0.5f);
    while (it > 0 && it * NT - (it * (it - 1)) / 2 > b) --it;
    while ((it + 1) * NT - ((it + 1) * it) / 2 <= b) ++it;
    const int jt = it + (b - (it * NT - (it * (it - 1)) / 2));

    // staging: wave w, inst m covers rows m*32 + w*8 + (l>>3), chunk l&7
    const bf16* gA = A + (size_t)(it * 128 + w * 8 + (l >> 3)) * DIM + (l & 7) * 8;
    const bf16* gB = A + (size_t)(jt * 128 + w * 8 + (l >> 3)) * DIM + (l & 7) * 8;

    f32x16 c00, c01, c10, c11;
#pragma unroll
    for (int r = 0; r < 16; ++r) { c00[r] = 0.f; c01[r] = 0.f; c10[r] = 0.f; c11[r] = 0.f; }

    const int arow = (w >> 1) * 64;
    const int brow = (w & 1) * 64;
    const int abase = (arow + lo) * 64 + hi * 8;  // element idx into As
    const int bbase = (brow + lo) * 64 + hi * 8;

#pragma unroll
    for (int ks = 0; ks < 4; ++ks) {
        if (ks) __syncthreads();
#pragma unroll
        for (int m = 0; m < 4; ++m) {
            GLOAD_LDS(gA + (size_t)(m * 32) * DIM + ks * 64, &As[m * 2048 + w * 512]);
            GLOAD_LDS(gB + (size_t)(m * 32) * DIM + ks * 64, &Bs[m * 2048 + w * 512]);
        }
        __syncthreads();
#pragma unroll
        for (int k16 = 0; k16 < 4; ++k16) {
            bf16x8 a0 = *(const bf16x8*)&As[abase + k16 * 16];
            bf16x8 a1 = *(const bf16x8*)&As[abase + 2048 + k16 * 16];
            bf16x8 b0 = *(const bf16x8*)&Bs[bbase + k16 * 16];
            bf16x8 b1 = *(const bf16x8*)&Bs[bbase + 2048 + k16 * 16];
            c00 = __builtin_amdgcn_mfma_f32_32x32x16_bf16(a0, b0, c00, 0, 0, 0);
            c01 = __builtin_amdgcn_mfma_f32_32x32x16_bf16(a0, b1, c01, 0, 0, 0);
            c10 = __builtin_amdgcn_mfma_f32_32x32x16_bf16(a1, b0, c10, 0, 0, 0);
            c11 = __builtin_amdgcn_mfma_f32_32x32x16_bf16(a1, b1, c11, 0, 0, 0);
        }
    }

    // exp((dot-1)/T) = exp2(dot*K1 - K1); diagonal is the provable row max
#pragma unroll
    for (int r = 0; r < 16; ++r) {
        c00[r] = __builtin_amdgcn_exp2f(fmaf(c00[r], K1C, -K1C));
        c01[r] = __builtin_amdgcn_exp2f(fmaf(c01[r], K1C, -K1C));
        c10[r] = __builtin_amdgcn_exp2f(fmaf(c10[r], K1C, -K1C));
        c11[r] = __builtin_amdgcn_exp2f(fmaf(c11[r], K1C, -K1C));
    }

    // col sums (cheap: per-lane over r, then 1 shfl across hi halves)
    {
        float v0 = 0.f, v1 = 0.f;
#pragma unroll
        for (int r = 0; r < 16; ++r) { v0 += c00[r] + c10[r]; v1 += c01[r] + c11[r]; }
        v0 += __shfl_xor(v0, 32);
        v1 += __shfl_xor(v1, 32);
        float* CsX = (w >> 1) ? CsB : CsA;  // waves sharing brow disambiguated
        CsX[brow + hi * 32 + lo] = hi ? v1 : v0;  // single writer per col
    }

    // row sums: pair partials then tree-reduce over the 32 lo lanes
    {
        float R0[16], R1[16];
#pragma unroll
        for (int r = 0; r < 16; ++r) { R0[r] = c00[r] + c01[r]; R1[r] = c10[r] + c11[r]; }
        float s0, s1;
        TREE16(R0, s0);
        TREE16(R1, s1);
        const int r = (lo >> 1) & 15;
        const int rowoff = (r & 3) + 8 * (r >> 2) + 4 * hi;  // C/D row mapping
        float* RsX = (w & 1) ? RsB : RsA;  // waves sharing arow disambiguated
        // even lo lanes own pair0 rows (arow+rowoff), odd own pair1 (+32)
        RsX[arow + ((l & 1) ? 32 : 0) + rowoff] = (l & 1) ? s1 : s0;
    }

    __syncthreads();
    if (tid < 128) {
        atomicAdd(&Tg[it * 128 + tid], RsA[tid] + RsB[tid]);
        if (jt != it) atomicAdd(&Tg[jt * 128 + tid], CsA[tid] + CsB[tid]);
    }
}

// Kernel 3: loss_i = log(T_i) + D_i, mean over rows.
__global__ void __launch_bounds__(256) final_kernel(const float* __restrict__ Tg,
                                                    const float* __restrict__ Dg,
                                                    float* __restrict__ out) {
    __shared__ float red[4];
    const int i = blockIdx.x * 256 + threadIdx.x;
    float c = (logf(Tg[i]) + Dg[i]) * (1.0f / (float)N_ROWS);
#pragma unroll
    for (int m = 1; m < 64; m <<= 1) c += __shfl_xor(c, m, 64);
    if ((threadIdx.x & 63) == 0) red[threadIdx.x >> 6] = c;
    __syncthreads();
    if (threadIdx.x == 0)
        atomicAdd(out, red[0] + red[1] + red[2] + red[3]);
}

extern "C" void kernel_launch(void* const* d_in, const int* in_sizes, int n_in,
                              void* d_out, int out_size, void* d_ws, size_t ws_size,
                              hipStream_t stream) {
    const float* emb = (const float*)d_in[0];
    float* out = (float*)d_out;
    bf16* Abf = (bf16*)d_ws;
    float* Tg = (float*)((char*)d_ws + WS_T_OFF);
    float* Dg = (float*)((char*)d_ws + WS_D_OFF);

    hipLaunchKernelGGL(normalize_kernel, dim3(N_ROWS / 4), dim3(256), 0, stream,
                       emb, Abf, Tg, Dg, out);
    hipLaunchKernelGGL(loss_kernel, dim3(NT * (NT + 1) / 2), dim3(256), 0, stream,
                       Abf, Tg);
    hipLaunchKernelGGL(final_kernel, dim3(N_ROWS / 256), dim3(256), 0, stream,
                       Tg, Dg, out);
}